// Round 1
// baseline (2775.800 us; speedup 1.0000x reference)
//
#include <hip/hip_runtime.h>

// MLP_1314259992962: 16x (Linear(128,128)+ReLU) chain + Linear(128,2), fp32 in/out.
// R3: operand-swapped MFMA + tau-permuted weight k-axis => the inter-layer
// transpose dissolves into pure register packing. Zero LDS, zero ds_read/write,
// zero v_perm. Evidence from R2: MfmaUtil 39% with ~10K cy/layer of LDS
// round-trip + unpack overhead at 1 wave/SIMD; LDS_BANK_CONFLICT 3.4e7.
//   - mfma(Wfrag, Xfrag): output m = lane&15 matches the consumer fragment's
//     row map; n lands on register indices (16nt+4q+r).
//   - prep_w stores W[n][tau(kappa)] with tau(32ks+8q+u)=16(2ks+(u>>2))+4q+(u&3);
//     both operands see the same permuted contraction axis => exact same math,
//     and producer registers ARE the consumer fragment after relu+split2.
//   - bias folded into acc init (per-quad float4, 1-deep rolling prefetch).
//   - MFMA order ks->term->mt: dependent MFMAs on one acc are 4 apart.
//   - last layer keeps fp32 acc in regs; final Linear(128,2) reads it directly.

#define LAYERS 16

typedef __bf16 bf16x8 __attribute__((ext_vector_type(8)));
typedef float  f32x4  __attribute__((ext_vector_type(4)));

__device__ __forceinline__ unsigned short f2bf(float f) {
  unsigned u = __float_as_uint(f);
  u += 0x7fffu + ((u >> 16) & 1u);       // round-to-nearest-even
  return (unsigned short)(u >> 16);
}

#if __has_builtin(__builtin_amdgcn_cvt_pk_bf16_f32)
typedef __bf16 bf16x2 __attribute__((ext_vector_type(2)));
__device__ __forceinline__ unsigned pkbf(float a, float b) {
  // low 16 = bf16(a), high 16 = bf16(b)
  return __builtin_bit_cast(unsigned, __builtin_amdgcn_cvt_pk_bf16_f32(a, b));
}
#else
__device__ __forceinline__ unsigned pkbf(float a, float b) {
  return (((unsigned)f2bf(b)) << 16) | (unsigned)f2bf(a);
}
#endif

// split (a,b) into packed-hi word and packed-lo word (bf16 pairs)
__device__ __forceinline__ void split2(float a, float b, unsigned &hw, unsigned &lw) {
  unsigned hp = pkbf(a, b);
  float la = a - __uint_as_float(hp << 16);
  float lb = b - __uint_as_float(hp & 0xffff0000u);
  hw = hp;
  lw = pkbf(la, lb);
}

// ---------------------------------------------------------------------------
// Prep: W fp32 [16][128][128] -> A-operand fragments, bf16 hi/lo, with the
// tau permutation on the k axis.
// Layout (dwords): [l][fragid = ((nt*4+ks)*2+term)][lane][d], 16384 dwords/layer.
// Element map: n = nt*16 + (lane&15); q = lane>>4;
//              k = ks*32 + (d>>1)*16 + q*4 + (d&1)*2  (+{0,1} within the pair)
// value = W[l][n][k]  (torch Linear: y = x @ W^T).
// ---------------------------------------------------------------------------
__global__ void prep_w(const float* __restrict__ W, unsigned* __restrict__ wf) {
  int t = blockIdx.x * 256 + threadIdx.x;    // 0 .. 262143
  int l     = t >> 14;
  int r     = t & 16383;
  int fi    = r >> 8;                        // 0..63
  int inner = r & 255;
  int lanei = inner >> 2;
  int d     = inner & 3;
  int term  = fi & 1;
  int ntks  = fi >> 1;
  int nt = ntks >> 2, ks = ntks & 3;
  int n = nt * 16 + (lanei & 15);
  int q = lanei >> 4;
  int k = ks * 32 + (d >> 1) * 16 + q * 4 + (d & 1) * 2;
  const float* wp = W + ((l * 128 + n) * 128 + k);
  float w0 = wp[0], w1 = wp[1];
  unsigned hp = pkbf(w0, w1);
  unsigned res;
  if (term == 0) {
    res = hp;
  } else {
    float h0 = __uint_as_float(hp << 16);
    float h1 = __uint_as_float(hp & 0xffff0000u);
    res = pkbf(w0 - h0, w1 - h1);
  }
  wf[t] = res;
}

// ---------------------------------------------------------------------------
// Main fused MLP kernel. grid = 4096 blocks x 256 threads. No LDS.
// Per wave: 64 rows. Fragments [mt][ks] (uint4 hi/lo), acc [nt][mt] (f32x4).
// ---------------------------------------------------------------------------
__launch_bounds__(256, 1)
__global__ void mlp_kernel(const unsigned* __restrict__ wf,
                           const float* __restrict__ bias,
                           const float* __restrict__ x,
                           const float* __restrict__ wout,
                           const float* __restrict__ bout,
                           float* __restrict__ out) {
  const int lane = threadIdx.x & 63;
  const int wave = threadIdx.x >> 6;
  const int c    = lane & 15;                // m-row lane index (both operands & C)
  const int q    = lane >> 4;                // quad
  const long rowbase = (long)blockIdx.x * 256 + wave * 64;

  uint4 aHi[4][4], aLo[4][4];                // input fragments  [mt][ks]
  uint4 nHi[4][4], nLo[4][4];                // output fragments [mt][ks]
  f32x4 acc[8][4];                           // [nt][mt]
  uint4 bhb[2][4], blb[2][4];                // W-fragment double buffer
  f32x4 bvq[2];                              // rolling per-quad bias (float4)

  // ---- initial weight prefetch (l=0, nt=0) — fly under the x load ----
  {
    const uint4* wl0 = (const uint4*)wf;
#pragma unroll
    for (int ks = 0; ks < 4; ++ks) {
      bhb[0][ks] = wl0[(ks * 2 + 0) * 64 + lane];
      blb[0][ks] = wl0[(ks * 2 + 1) * 64 + lane];
    }
  }
  bvq[0] = *(const f32x4*)(bias + q * 4);

  // ---- layer-0 input: load x rows with tau-mapped columns, split hi/lo ----
  {
    const float* xb = x + rowbase * 128;
#pragma unroll
    for (int mt = 0; mt < 4; ++mt) {
      const float* xr = xb + (mt * 16 + c) * 128 + q * 4;
#pragma unroll
      for (int ks = 0; ks < 4; ++ks) {
        f32x4 v0 = *(const f32x4*)(xr + ks * 32);        // k = 32ks+4q+{0..3}
        f32x4 v1 = *(const f32x4*)(xr + ks * 32 + 16);   // k = 32ks+16+4q+{0..3}
        uint4 hh, ll;
        split2(v0[0], v0[1], hh.x, ll.x);
        split2(v0[2], v0[3], hh.y, ll.y);
        split2(v1[0], v1[1], hh.z, ll.z);
        split2(v1[2], v1[3], hh.w, ll.w);
        aHi[mt][ks] = hh;
        aLo[mt][ks] = ll;
      }
    }
  }

// One layer: MFMAs into acc[nt][mt]; if DO_PACK, relu+split each nt-pair into
// nHi/nLo right after the pair completes (schedules under later nt's MFMAs).
#define MLP_LAYER(lv, AIH, AIL, DO_PACK)                                       \
  {                                                                            \
    const int _l = (lv);                                                       \
    const uint4* wl = (const uint4*)(wf) + (size_t)_l * 4096;                  \
    _Pragma("unroll")                                                          \
    for (int nt = 0; nt < 8; ++nt) {                                           \
      {                                                                        \
        f32x4 ini = bvq[nt & 1];  /* bias[l][16nt+4q+r] pre-loaded into acc */ \
        _Pragma("unroll")                                                      \
        for (int mt = 0; mt < 4; ++mt) acc[nt][mt] = ini;                      \
      }                                                                        \
      /* prefetch: next nt of this layer, or nt=0 of the next layer */         \
      if (nt < 7) {                                                            \
        bvq[(nt + 1) & 1] =                                                    \
            *(const f32x4*)(bias + _l * 128 + (nt + 1) * 16 + q * 4);          \
        _Pragma("unroll")                                                      \
        for (int ks = 0; ks < 4; ++ks) {                                       \
          bhb[(nt + 1) & 1][ks] = wl[(((nt + 1) * 4 + ks) * 2 + 0) * 64 + lane]; \
          blb[(nt + 1) & 1][ks] = wl[(((nt + 1) * 4 + ks) * 2 + 1) * 64 + lane]; \
        }                                                                      \
      } else if (_l < LAYERS - 1) {                                            \
        bvq[0] = *(const f32x4*)(bias + (_l + 1) * 128 + q * 4);               \
        _Pragma("unroll")                                                      \
        for (int ks = 0; ks < 4; ++ks) {                                       \
          bhb[0][ks] = wl[4096 + (ks * 2 + 0) * 64 + lane];                    \
          blb[0][ks] = wl[4096 + (ks * 2 + 1) * 64 + lane];                    \
        }                                                                      \
      }                                                                        \
      /* MFMA block: ks -> term -> mt, dependent-acc distance = 4 */           \
      _Pragma("unroll")                                                        \
      for (int ks = 0; ks < 4; ++ks) {                                         \
        bf16x8 Wh = __builtin_bit_cast(bf16x8, bhb[nt & 1][ks]);               \
        bf16x8 Wl = __builtin_bit_cast(bf16x8, blb[nt & 1][ks]);               \
        _Pragma("unroll")                                                      \
        for (int mt = 0; mt < 4; ++mt)                                         \
          acc[nt][mt] = __builtin_amdgcn_mfma_f32_16x16x32_bf16(               \
              Wh, __builtin_bit_cast(bf16x8, AIH[mt][ks]), acc[nt][mt], 0, 0, 0); \
        _Pragma("unroll")                                                      \
        for (int mt = 0; mt < 4; ++mt)                                         \
          acc[nt][mt] = __builtin_amdgcn_mfma_f32_16x16x32_bf16(               \
              Wl, __builtin_bit_cast(bf16x8, AIH[mt][ks]), acc[nt][mt], 0, 0, 0); \
        _Pragma("unroll")                                                      \
        for (int mt = 0; mt < 4; ++mt)                                         \
          acc[nt][mt] = __builtin_amdgcn_mfma_f32_16x16x32_bf16(               \
              Wh, __builtin_bit_cast(bf16x8, AIL[mt][ks]), acc[nt][mt], 0, 0, 0); \
      }                                                                        \
      /* pack nt-pair -> consumer fragment ks' = nt>>1 (pure registers) */     \
      if ((DO_PACK) && (nt & 1)) {                                             \
        const int kso = nt >> 1;                                               \
        _Pragma("unroll")                                                      \
        for (int mt = 0; mt < 4; ++mt) {                                       \
          float e0 = fmaxf(acc[nt - 1][mt][0], 0.0f);                          \
          float e1 = fmaxf(acc[nt - 1][mt][1], 0.0f);                          \
          float e2 = fmaxf(acc[nt - 1][mt][2], 0.0f);                          \
          float e3 = fmaxf(acc[nt - 1][mt][3], 0.0f);                          \
          float f0 = fmaxf(acc[nt][mt][0], 0.0f);                              \
          float f1 = fmaxf(acc[nt][mt][1], 0.0f);                              \
          float f2 = fmaxf(acc[nt][mt][2], 0.0f);                              \
          float f3 = fmaxf(acc[nt][mt][3], 0.0f);                              \
          uint4 hh, ll;                                                        \
          split2(e0, e1, hh.x, ll.x);                                          \
          split2(e2, e3, hh.y, ll.y);                                          \
          split2(f0, f1, hh.z, ll.z);                                          \
          split2(f2, f3, hh.w, ll.w);                                          \
          nHi[mt][kso] = hh;                                                   \
          nLo[mt][kso] = ll;                                                   \
        }                                                                      \
      }                                                                        \
    }                                                                          \
  }

#pragma unroll 1
  for (int l = 0; l < LAYERS - 1; ++l) {
    MLP_LAYER(l, aHi, aLo, 1);
    // rotate fragments for the next layer (register moves, in MFMA shadow)
#pragma unroll
    for (int mt = 0; mt < 4; ++mt)
#pragma unroll
      for (int ks = 0; ks < 4; ++ks) {
        aHi[mt][ks] = nHi[mt][ks];
        aLo[mt][ks] = nLo[mt][ks];
      }
  }
  // last relu-layer: keep fp32 acc in registers, no pack
  MLP_LAYER(LAYERS - 1, aHi, aLo, 0);

  // ---- final Linear(128,2) straight from acc (fp32 math) ----
  f32x4 wo0[8], wo1[8];
#pragma unroll
  for (int nt = 0; nt < 8; ++nt) {
    wo0[nt] = *(const f32x4*)(wout + nt * 16 + q * 4);
    wo1[nt] = *(const f32x4*)(wout + 128 + nt * 16 + q * 4);
  }
  float bo0 = bout[0], bo1 = bout[1];
#pragma unroll
  for (int mt = 0; mt < 4; ++mt) {
    float s0 = 0.0f, s1 = 0.0f;
#pragma unroll
    for (int nt = 0; nt < 8; ++nt) {
#pragma unroll
      for (int r = 0; r < 4; ++r) {
        float v = fmaxf(acc[nt][mt][r], 0.0f);   // h[m=16mt+c][n=16nt+4q+r]
        s0 = fmaf(v, wo0[nt][r], s0);
        s1 = fmaf(v, wo1[nt][r], s1);
      }
    }
    // reduce the 4 quads (n-partials) of each row
    s0 += __shfl_xor(s0, 16); s0 += __shfl_xor(s0, 32);
    s1 += __shfl_xor(s1, 16); s1 += __shfl_xor(s1, 32);
    if (q == 0) {
      long r = rowbase + mt * 16 + c;
      float2 o;
      o.x = s0 + bo0;
      o.y = s1 + bo1;
      *(float2*)(out + r * 2) = o;
    }
  }
}

extern "C" void kernel_launch(void* const* d_in, const int* in_sizes, int n_in,
                              void* d_out, int out_size, void* d_ws, size_t ws_size,
                              hipStream_t stream) {
  (void)in_sizes; (void)n_in; (void)out_size; (void)ws_size;
  const float* x    = (const float*)d_in[0];   // [1048576][128]
  const float* W    = (const float*)d_in[1];   // [16][128][128]
  const float* b    = (const float*)d_in[2];   // [16][128]
  const float* wout = (const float*)d_in[3];   // [2][128]
  const float* bout = (const float*)d_in[4];   // [2]
  float* out = (float*)d_out;                  // [1048576][2]
  unsigned* wf = (unsigned*)d_ws;              // 1 MB fragment-ordered split weights

  prep_w<<<dim3(1024), dim3(256), 0, stream>>>(W, wf);
  mlp_kernel<<<dim3(4096), dim3(256), 0, stream>>>(wf, b, x, wout, bout, out);
}